// Round 1
// baseline (3807.276 us; speedup 1.0000x reference)
//
#include <hip/hip_runtime.h>
#include <hip/hip_bf16.h>
#include <math.h>
#include <stdint.h>

#define HID 512
#define NB  512      // batch
#define TT  128      // encoder sequence length
#define HOR 24       // decoder horizon
#define G4  2048     // 4*HID

typedef __attribute__((ext_vector_type(8))) short bf16x8;
typedef __attribute__((ext_vector_type(4))) float f32x4;

struct CellParams {
  const __hip_bfloat16* A1;   // [NB][512] recurrent/first input (bf16)
  const __hip_bfloat16* A2;   // [NB][512] second K-block (bf16) or null
  const __hip_bfloat16* W;    // [2048][Kt] gate-interleaved weights (bf16)
  const float* bias;          // [2048] combined bias, interleaved
  const float* Wx;            // [2048][2] input-proj weights (interleaved) or null
  const float* xv;            // x input; row b at xv[b*xstride +0,+1]
  long xstride;
  float* c;                   // [NB][512] cell state fp32 (in-place)
  __hip_bfloat16* hout;       // [NB][512] new h (bf16)
  int Kt;                     // 512 or 1024 (W row stride)
};

__device__ __forceinline__ void gl_lds16(void* lds, const void* g) {
  __builtin_amdgcn_global_load_lds((const __attribute__((address_space(1))) void*)g,
                                   (__attribute__((address_space(3))) void*)lds, 16, 0, 0);
}

__device__ __forceinline__ float sigm(float x) { return 1.0f / (1.0f + expf(-x)); }

// One LSTM cell step as a fused GEMM+epilogue.
// Gate matrix G[b, n'] with n' = 4*j + g (g in {i,f,g,o}).
// Block tile 64(M=batch) x 64(N=gates) ; grid 8 x 32 = 256 blocks; 4 waves of 32x32.
__device__ void cell_body(const CellParams p, int blk, char* smem) {
  const int tid = threadIdx.x;
  const int mt = blk & 7, nt = blk >> 3;
  const int m0 = mt * 64, n0 = nt * 64;

  __hip_bfloat16* sA = (__hip_bfloat16*)smem;             // 64x64 bf16, octet layout (8KB)
  __hip_bfloat16* sB = (__hip_bfloat16*)(smem + 8192);    // 8KB
  float* gbuf = (float*)(smem + 16384);                   // 64 x 68 fp32 (padded)

  const int lane = tid & 63, wv = tid >> 6;
  const int wm = (wv >> 1) * 32, wn = (wv & 1) * 32;
  const int mrow = lane & 15, quad = lane >> 4;

  f32x4 acc00 = {0.f,0.f,0.f,0.f}, acc01 = acc00, acc10 = acc00, acc11 = acc00;

  const int iters = p.Kt >> 6;
  for (int it = 0; it < iters; ++it) {
    const int kc0 = it << 6;
    const __hip_bfloat16* Asrc; int kloc;
    if (kc0 < 512) { Asrc = p.A1; kloc = kc0; } else { Asrc = p.A2; kloc = kc0 - 512; }
#pragma unroll
    for (int i = 0; i < 2; ++i) {
      int Gi = i * 256 + tid;        // 0..511 ; chunk = octet*64 + row
      int o = Gi >> 6, r = Gi & 63;
      gl_lds16((char*)sA + (size_t)Gi * 16, Asrc + (size_t)(m0 + r) * 512 + kloc + o * 8);
      gl_lds16((char*)sB + (size_t)Gi * 16, p.W + (size_t)(n0 + r) * p.Kt + kc0 + o * 8);
    }
    __syncthreads();   // drains vmcnt(0): global_load_lds complete
#pragma unroll
    for (int kh = 0; kh < 2; ++kh) {
      int ob = (kh << 2) + quad;     // octet index for this lane's K-slice
      bf16x8 a0 = *(bf16x8*)((char*)sA + (size_t)((ob << 6) + wm + mrow) * 16);
      bf16x8 a1 = *(bf16x8*)((char*)sA + (size_t)((ob << 6) + wm + 16 + mrow) * 16);
      bf16x8 b0 = *(bf16x8*)((char*)sB + (size_t)((ob << 6) + wn + mrow) * 16);
      bf16x8 b1 = *(bf16x8*)((char*)sB + (size_t)((ob << 6) + wn + 16 + mrow) * 16);
      acc00 = __builtin_amdgcn_mfma_f32_16x16x32_bf16(a0, b0, acc00, 0, 0, 0);
      acc01 = __builtin_amdgcn_mfma_f32_16x16x32_bf16(a0, b1, acc01, 0, 0, 0);
      acc10 = __builtin_amdgcn_mfma_f32_16x16x32_bf16(a1, b0, acc10, 0, 0, 0);
      acc11 = __builtin_amdgcn_mfma_f32_16x16x32_bf16(a1, b1, acc11, 0, 0, 0);
    }
    __syncthreads();
  }

  // dump accumulators to LDS (C/D layout: col=lane&15, row=quad*4+reg)
#pragma unroll
  for (int r = 0; r < 4; ++r) {
    gbuf[(size_t)(wm + quad * 4 + r) * 68 + wn + mrow]            = acc00[r];
    gbuf[(size_t)(wm + quad * 4 + r) * 68 + wn + 16 + mrow]       = acc01[r];
    gbuf[(size_t)(wm + 16 + quad * 4 + r) * 68 + wn + mrow]       = acc10[r];
    gbuf[(size_t)(wm + 16 + quad * 4 + r) * 68 + wn + 16 + mrow]  = acc11[r];
  }
  __syncthreads();

  // fused LSTM epilogue: each thread handles 4 (b, j) cells
  const int jl = tid & 15;
  const int j0 = n0 >> 2;
#pragma unroll
  for (int ps = 0; ps < 4; ++ps) {
    int bl = (tid >> 4) + ps * 16;
    int b = m0 + bl;
    f32x4 gv = *(f32x4*)&gbuf[(size_t)bl * 68 + jl * 4];
    int n4 = n0 + jl * 4;
    f32x4 bz = *(const f32x4*)&p.bias[n4];
    float gi = gv[0] + bz[0], gf = gv[1] + bz[1], gg = gv[2] + bz[2], go = gv[3] + bz[3];
    if (p.Wx) {
      float x0 = p.xv[(size_t)b * p.xstride];
      float x1 = p.xv[(size_t)b * p.xstride + 1];
      f32x4 w01 = *(const f32x4*)&p.Wx[(size_t)n4 * 2];
      f32x4 w23 = *(const f32x4*)&p.Wx[(size_t)n4 * 2 + 4];
      gi += x0 * w01[0] + x1 * w01[1];
      gf += x0 * w01[2] + x1 * w01[3];
      gg += x0 * w23[0] + x1 * w23[1];
      go += x0 * w23[2] + x1 * w23[3];
    }
    float iv = sigm(gi), fv = sigm(gf), gvv = tanhf(gg), ov = sigm(go);
    size_t idx = (size_t)b * 512 + (j0 + jl);
    float cv = fv * p.c[idx] + iv * gvv;
    p.c[idx] = cv;
    p.hout[idx] = __float2bfloat16(ov * tanhf(cv));
  }
}

__global__ __launch_bounds__(256) void enc_step_kernel(CellParams p0, CellParams p1,
                                                       int act0, int act1) {
  __shared__ __align__(16) char smem[16384 + 64 * 68 * 4];
  if (blockIdx.x < 256) { if (act0) cell_body(p0, blockIdx.x, smem); }
  else if (act1) cell_body(p1, blockIdx.x - 256, smem);
}

__global__ __launch_bounds__(256) void cell_kernel(CellParams p) {
  __shared__ __align__(16) char smem[16384 + 64 * 68 * 4];
  cell_body(p, blockIdx.x, smem);
}

// Build gate-interleaved bf16 weights + combined fp32 biases.
__global__ void prep_weights(
    const float* eWih0, const float* eWhh0, const float* ebih0, const float* ebhh0,
    const float* eWih1, const float* eWhh1, const float* ebih1, const float* ebhh1,
    const float* dWih0, const float* dWhh0, const float* dbih0, const float* dbhh0,
    const float* dWih1, const float* dWhh1, const float* dbih1, const float* dbhh1,
    __hip_bfloat16* W0r, __hip_bfloat16* W1c, __hip_bfloat16* Wd0r, __hip_bfloat16* Wd1c,
    float* b0r, float* b1r, float* bd0r, float* bd1r, float* Wx0r, float* Wxd0r) {
  long idx = (long)blockIdx.x * blockDim.x + threadIdx.x;
  if (idx >= (long)G4 * 3072) return;
  int np = (int)(idx / 3072), kk = (int)(idx % 3072);
  int g = np & 3, j = np >> 2;
  int srow = g * HID + j;
  if (kk < 512) {
    W0r[(size_t)np * 512 + kk] = __float2bfloat16(eWhh0[(size_t)srow * 512 + kk]);
  } else if (kk < 1536) {
    int k2 = kk - 512;
    float v = (k2 < 512) ? eWih1[(size_t)srow * 512 + k2] : eWhh1[(size_t)srow * 512 + (k2 - 512)];
    W1c[(size_t)np * 1024 + k2] = __float2bfloat16(v);
  } else if (kk < 2048) {
    int k2 = kk - 1536;
    Wd0r[(size_t)np * 512 + k2] = __float2bfloat16(dWhh0[(size_t)srow * 512 + k2]);
  } else {
    int k2 = kk - 2048;
    float v = (k2 < 512) ? dWih1[(size_t)srow * 512 + k2] : dWhh1[(size_t)srow * 512 + (k2 - 512)];
    Wd1c[(size_t)np * 1024 + k2] = __float2bfloat16(v);
  }
  if (kk == 0) {
    b0r[np]  = ebih0[srow] + ebhh0[srow];
    b1r[np]  = ebih1[srow] + ebhh1[srow];
    bd0r[np] = dbih0[srow] + dbhh0[srow];
    bd1r[np] = dbih1[srow] + dbhh1[srow];
    Wx0r[np * 2]     = eWih0[srow * 2];
    Wx0r[np * 2 + 1] = eWih0[srow * 2 + 1];
    Wxd0r[np * 2]     = dWih0[srow * 2];
    Wxd0r[np * 2 + 1] = dWih0[srow * 2 + 1];
  }
}

// pred = dh2 @ fcW.T + fcb ; writes d_out[:, s, :] and feedback buffer
__global__ __launch_bounds__(256) void pred_kernel(const __hip_bfloat16* h2,
                                                   const float* fcW, const float* fcb,
                                                   float* outp, float* predbuf, int s) {
  int wvi = threadIdx.x >> 6, lane = threadIdx.x & 63;
  int b = blockIdx.x * 4 + wvi;
  float s0 = 0.f, s1 = 0.f;
  for (int k = lane; k < 512; k += 64) {
    float hv = __bfloat162float(h2[(size_t)b * 512 + k]);
    s0 += hv * fcW[k];
    s1 += hv * fcW[512 + k];
  }
  for (int off = 32; off; off >>= 1) {
    s0 += __shfl_down(s0, off);
    s1 += __shfl_down(s1, off);
  }
  if (lane == 0) {
    float p0 = s0 + fcb[0], p1 = s1 + fcb[1];
    outp[(size_t)b * (HOR * 2) + s * 2]     = p0;
    outp[(size_t)b * (HOR * 2) + s * 2 + 1] = p1;
    predbuf[b * 2]     = p0;
    predbuf[b * 2 + 1] = p1;
  }
}

extern "C" void kernel_launch(void* const* d_in, const int* in_sizes, int n_in,
                              void* d_out, int out_size, void* d_ws, size_t ws_size,
                              hipStream_t stream) {
  (void)in_sizes; (void)n_in; (void)out_size; (void)ws_size;
  const float* x     = (const float*)d_in[0];
  const float* eWih0 = (const float*)d_in[1];
  const float* eWhh0 = (const float*)d_in[2];
  const float* ebih0 = (const float*)d_in[3];
  const float* ebhh0 = (const float*)d_in[4];
  const float* eWih1 = (const float*)d_in[5];
  const float* eWhh1 = (const float*)d_in[6];
  const float* ebih1 = (const float*)d_in[7];
  const float* ebhh1 = (const float*)d_in[8];
  const float* dWih0 = (const float*)d_in[9];
  const float* dWhh0 = (const float*)d_in[10];
  const float* dbih0 = (const float*)d_in[11];
  const float* dbhh0 = (const float*)d_in[12];
  const float* dWih1 = (const float*)d_in[13];
  const float* dWhh1 = (const float*)d_in[14];
  const float* dbih1 = (const float*)d_in[15];
  const float* dbhh1 = (const float*)d_in[16];
  const float* fcW   = (const float*)d_in[17];
  const float* fcb   = (const float*)d_in[18];

  char* ws = (char*)d_ws;
  size_t off = 0;
  auto alloc = [&](size_t bytes) -> char* {
    char* pp = ws + off;
    off = (off + bytes + 255) & ~(size_t)255;
    return pp;
  };

  __hip_bfloat16* W0r  = (__hip_bfloat16*)alloc((size_t)G4 * 512 * 2);
  __hip_bfloat16* W1c  = (__hip_bfloat16*)alloc((size_t)G4 * 1024 * 2);
  __hip_bfloat16* Wd0r = (__hip_bfloat16*)alloc((size_t)G4 * 512 * 2);
  __hip_bfloat16* Wd1c = (__hip_bfloat16*)alloc((size_t)G4 * 1024 * 2);
  float* b0r  = (float*)alloc(G4 * 4);
  float* b1r  = (float*)alloc(G4 * 4);
  float* bd0r = (float*)alloc(G4 * 4);
  float* bd1r = (float*)alloc(G4 * 4);
  float* Wx0r  = (float*)alloc(G4 * 2 * 4);
  float* Wxd0r = (float*)alloc(G4 * 2 * 4);

  char* zbase = ws + off;
  __hip_bfloat16* h0b[2], *h1b[2];
  h0b[0] = (__hip_bfloat16*)alloc((size_t)NB * 512 * 2);
  h0b[1] = (__hip_bfloat16*)alloc((size_t)NB * 512 * 2);
  h1b[0] = (__hip_bfloat16*)alloc((size_t)NB * 512 * 2);
  h1b[1] = (__hip_bfloat16*)alloc((size_t)NB * 512 * 2);
  float* c0 = (float*)alloc((size_t)NB * 512 * 4);
  float* c1 = (float*)alloc((size_t)NB * 512 * 4);
  float* pb[2];
  pb[0] = (float*)alloc(NB * 2 * 4);
  pb[1] = (float*)alloc(NB * 2 * 4);
  size_t zbytes = (size_t)((ws + off) - zbase);

  hipMemsetAsync(zbase, 0, zbytes, stream);
  prep_weights<<<((long)G4 * 3072 + 255) / 256, 256, 0, stream>>>(
      eWih0, eWhh0, ebih0, ebhh0, eWih1, eWhh1, ebih1, ebhh1,
      dWih0, dWhh0, dbih0, dbhh0, dWih1, dWhh1, dbih1, dbhh1,
      W0r, W1c, Wd0r, Wd1c, b0r, b1r, bd0r, bd1r, Wx0r, Wxd0r);

  // Encoder: layer0 at step s, layer1 pipelined one step behind (computes h1[s-1]).
  for (int s = 0; s <= TT; ++s) {
    CellParams p0 = {}, p1 = {};
    p0.A1 = h0b[(s + 1) & 1]; p0.A2 = nullptr;
    p0.W = W0r; p0.bias = b0r; p0.Wx = Wx0r;
    p0.xv = x + (size_t)s * 2; p0.xstride = (long)TT * 2;
    p0.c = c0; p0.hout = h0b[s & 1]; p0.Kt = 512;

    p1.A1 = h0b[(s + 1) & 1];        // h0[s-1]
    p1.A2 = h1b[s & 1];              // h1[s-2]
    p1.W = W1c; p1.bias = b1r; p1.Wx = nullptr; p1.xv = nullptr; p1.xstride = 0;
    p1.c = c1; p1.hout = h1b[(s + 1) & 1]; p1.Kt = 1024;

    enc_step_kernel<<<512, 256, 0, stream>>>(p0, p1, (s < TT) ? 1 : 0, (s >= 1) ? 1 : 0);
  }

  // Decoder: 24 steps of cell1 -> cell2 -> pred
  for (int d = 0; d < HOR; ++d) {
    CellParams q1 = {}, q2 = {};
    q1.A1 = h0b[(d + 1) & 1]; q1.A2 = nullptr;
    q1.W = Wd0r; q1.bias = bd0r; q1.Wx = Wxd0r;
    q1.xv = pb[(d + 1) & 1]; q1.xstride = 2;
    q1.c = c0; q1.hout = h0b[d & 1]; q1.Kt = 512;
    cell_kernel<<<256, 256, 0, stream>>>(q1);

    q2.A1 = h0b[d & 1];              // new dh1
    q2.A2 = h1b[(d + 1) & 1];        // prev dh2
    q2.W = Wd1c; q2.bias = bd1r; q2.Wx = nullptr; q2.xv = nullptr; q2.xstride = 0;
    q2.c = c1; q2.hout = h1b[d & 1]; q2.Kt = 1024;
    cell_kernel<<<256, 256, 0, stream>>>(q2);

    pred_kernel<<<NB / 4, 256, 0, stream>>>(h1b[d & 1], fcW, fcb, (float*)d_out, pb[d & 1], d);
  }
}